// Round 12
// baseline (1127.402 us; speedup 1.0000x reference)
//
#include <hip/hip_runtime.h>
#include <hip/hip_fp16.h>
#include <math.h>

#define HC 16      // hidden
#define INC 128    // in_channels
#define OUTC 32    // out_channels
#define BKT_SHIFT 8            // 256 nodes per bucket (slab layout only)
#define CAP 9216               // bucket edge capacity: E[8192] + 11 sigma

typedef _Float16 f16;
typedef _Float16 f16x8 __attribute__((ext_vector_type(8)));

// ================= CSR build v3: direct global-atomic scatter =================
// Replaces bin_kernel + bucketize (two LDS staging round-trips, ~100us) with:
//   memset(deg) -> degree_kernel -> scan_gemm_kernel -> scatter_kernel

// (A) degree histogram: 6.4M fire-and-forget atomics on 800KB (L2-resident)
__global__ void __launch_bounds__(256) degree_kernel(
        const int* __restrict__ dst, int* __restrict__ deg, int e) {
    int q = blockIdx.x * blockDim.x + threadIdx.x;
    int j = q * 4;
    if (j + 3 < e) {
        int4 d4 = *(const int4*)(dst + j);
        atomicAdd(&deg[d4.x], 1);
        atomicAdd(&deg[d4.y], 1);
        atomicAdd(&deg[d4.z], 1);
        atomicAdd(&deg[d4.w], 1);
    } else {
        for (; j < e; ++j) atomicAdd(&deg[dst[j]], 1);
    }
}

// (B) per-bucket scan of degrees -> row_beg/dinv; row_end initialized as the
// scatter CURSOR (after scatter completes it equals the true row end).
// gemm1 fused: same 256-node/block decomposition, dinv stays in register.
__global__ void __launch_bounds__(256) scan_gemm_kernel(
        const int* __restrict__ deg, const float* __restrict__ x,
        const float* __restrict__ W1, int* __restrict__ row_beg,
        int* __restrict__ row_end, float* __restrict__ dinv,
        f16* __restrict__ hd1, int n) {
    __shared__ float sW[INC * HC];   // 8 KB
    __shared__ int wsum2[4];
    int tid = threadIdx.x;
    int node0 = blockIdx.x << BKT_SHIFT;
    int node = node0 + tid;
    int d = (node < n) ? deg[node] : 0;
    // exclusive scan over 256 degrees: shfl wave-scan (4 waves) + fixup
    int lane = tid & 63, w = tid >> 6;
    int vv = d;
#pragma unroll
    for (int s = 1; s < 64; s <<= 1) {
        int u = __shfl_up(vv, s, 64);
        if (lane >= s) vv += u;
    }
    if (lane == 63) wsum2[w] = vv;
    __syncthreads();
    int wb = 0;
#pragma unroll
    for (int w2 = 0; w2 < 4; ++w2) wb += (w2 < w) ? wsum2[w2] : 0;
    int excl = wb + vv - d;
    int base = blockIdx.x * CAP;
    float di = rsqrtf((float)d + 1.0f);   // +1 self-loop
    if (node < n) {
        row_beg[node] = base + excl;
        row_end[node] = base + excl;      // cursor start == beg
        dinv[node] = di;
    }
    // ===== fused gemm1 (R1-proven pattern) =====
    for (int i = tid; i < INC * HC; i += 256) sW[i] = W1[i];
    __syncthreads();
    if (node >= n) return;
    const float4* xr = (const float4*)(x + (size_t)node * INC);
    float acc[HC];
#pragma unroll
    for (int f = 0; f < HC; ++f) acc[f] = 0.f;
#pragma unroll 4
    for (int k4 = 0; k4 < INC / 4; ++k4) {
        float4 v = xr[k4];
        const float* wp = &sW[k4 * 4 * HC];
#pragma unroll
        for (int f = 0; f < HC; ++f)
            acc[f] += v.x * wp[f] + v.y * wp[HC + f] + v.z * wp[2 * HC + f] + v.w * wp[3 * HC + f];
    }
    union { f16 h[HC]; float4 q[2]; } u;
#pragma unroll
    for (int f = 0; f < HC; ++f) u.h[f] = (f16)(acc[f] * di);
    float4* hl = (float4*)(hd1 + (size_t)node * HC);
    hl[0] = u.q[0];
    hl[1] = u.q[1];
}

// (C) scatter: pos = atomicAdd(cursor[dst]) ; csrbuf[pos] = src.
// 200K cursors = low contention; 4B scattered writes L2-aggregate (~16/line).
__global__ void __launch_bounds__(256) scatter_kernel(
        const int* __restrict__ src, const int* __restrict__ dst,
        int* __restrict__ row_end, int* __restrict__ csrbuf, int e) {
    int q = blockIdx.x * blockDim.x + threadIdx.x;
    int j = q * 4;
    if (j + 3 < e) {
        int4 s4 = *(const int4*)(src + j);
        int4 d4 = *(const int4*)(dst + j);
        int p0 = atomicAdd(&row_end[d4.x], 1);
        int p1 = atomicAdd(&row_end[d4.y], 1);
        int p2 = atomicAdd(&row_end[d4.z], 1);
        int p3 = atomicAdd(&row_end[d4.w], 1);
        csrbuf[p0] = s4.x;
        csrbuf[p1] = s4.y;
        csrbuf[p2] = s4.z;
        csrbuf[p3] = s4.w;
    } else {
        for (; j < e; ++j) {
            int p = atomicAdd(&row_end[dst[j]], 1);
            csrbuf[p] = src[j];
        }
    }
}

// ===== wide-load gather core: lane l of 16-lane group = (half h=l&1, slot k=l>>1)
// each lane strides edges by 8, loading 16B (8 f16) per edge -> 8x fewer VMEM
// requests than 16x2B. Returns feature-f sum (incl self-loop) in "lane f" layout.
__device__ __forceinline__ float gather_row16(
        const f16* __restrict__ hd, const int* __restrict__ csr,
        int beg, int end, int node, int f) {
    int h = f & 1;           // which 16B half
    int k = f >> 1;          // edge slot 0..7
    float a0 = 0.f, a1 = 0.f, a2 = 0.f, a3 = 0.f;
    float a4 = 0.f, a5 = 0.f, a6 = 0.f, a7 = 0.f;
    int jj = beg + k;
    if (jj < end) {
        int s = csr[jj];
        jj += 8;
        for (; jj < end; jj += 8) {
            int sn = csr[jj];   // prefetch next edge's src (hides csr latency)
            f16x8 v = *(const f16x8*)(hd + ((size_t)s << 4) + (h << 3));
            a0 += (float)v[0]; a1 += (float)v[1]; a2 += (float)v[2]; a3 += (float)v[3];
            a4 += (float)v[4]; a5 += (float)v[5]; a6 += (float)v[6]; a7 += (float)v[7];
            s = sn;
        }
        f16x8 v = *(const f16x8*)(hd + ((size_t)s << 4) + (h << 3));
        a0 += (float)v[0]; a1 += (float)v[1]; a2 += (float)v[2]; a3 += (float)v[3];
        a4 += (float)v[4]; a5 += (float)v[5]; a6 += (float)v[6]; a7 += (float)v[7];
    }
    // reduce across the 8 lanes sharing this half (xor over slot bits = lane bits 1..3)
#pragma unroll
    for (int m = 2; m <= 8; m <<= 1) {
        a0 += __shfl_xor(a0, m, 16); a1 += __shfl_xor(a1, m, 16);
        a2 += __shfl_xor(a2, m, 16); a3 += __shfl_xor(a3, m, 16);
        a4 += __shfl_xor(a4, m, 16); a5 += __shfl_xor(a5, m, 16);
        a6 += __shfl_xor(a6, m, 16); a7 += __shfl_xor(a7, m, 16);
    }
    // rearrange to "lane f holds feature f". Source-side select: lane l exports
    // element (l>>1)=k of its half (l&1)=h, i.e. feature (h*8 + k). Destination f
    // needs half f>>3, element f&7 -> source lane ((f&7)<<1)|(f>>3).
    float e = a0;
    e = (k == 1) ? a1 : e;
    e = (k == 2) ? a2 : e;
    e = (k == 3) ? a3 : e;
    e = (k == 4) ? a4 : e;
    e = (k == 5) ? a5 : e;
    e = (k == 6) ? a6 : e;
    e = (k == 7) ? a7 : e;
    float gsum = __shfl(e, ((f & 7) << 1) | (f >> 3), 16);
    // self-loop term
    return gsum + (float)hd[(size_t)node * HC + f];
}

// ===== layer-1 gather + fused W2 =====
__global__ void __launch_bounds__(256) gather_fuse1_kernel(
        const f16* __restrict__ hd1, const int* __restrict__ csr,
        const int* __restrict__ row_beg, const int* __restrict__ row_end,
        const float* __restrict__ dinv, const float* __restrict__ b1,
        const float* __restrict__ W2, f16* __restrict__ hd2, int n) {
    __shared__ float sW[HC * 17];    // pitch 17: conflict-free column reads
    __shared__ float sb[HC];
    if (threadIdx.x < HC * HC) sW[(threadIdx.x >> 4) * 17 + (threadIdx.x & 15)] = W2[threadIdx.x];
    if (threadIdx.x < HC) sb[threadIdx.x] = b1[threadIdx.x];
    __syncthreads();
    int t = blockIdx.x * blockDim.x + threadIdx.x;
    int node = t >> 4;
    if (node >= n) return;
    int f = t & 15;
    float acc = gather_row16(hd1, csr, row_beg[node], row_end[node], node, f);
    float di = dinv[node];
    float h1 = fmaxf(acc * di + sb[f], 0.f);
    float a2 = 0.f;
#pragma unroll
    for (int k = 0; k < HC; ++k) {
        float hk = __shfl(h1, k, 16);
        a2 += hk * sW[k * 17 + f];
    }
    hd2[(size_t)node * HC + f] = (f16)(a2 * di);
}

// ===== layer-2 gather + fused GRU + FC =====
__global__ void __launch_bounds__(256) gather_final_kernel(
        const f16* __restrict__ hd2, const int* __restrict__ csr,
        const int* __restrict__ row_beg, const int* __restrict__ row_end,
        const float* __restrict__ dinv, const float* __restrict__ b2,
        const float* __restrict__ w_ih, const float* __restrict__ b_ih,
        const float* __restrict__ b_hh, const float* __restrict__ Wfc,
        const float* __restrict__ bfc, float* __restrict__ out, int n) {
    __shared__ float s_wih[3 * HC * 17];   // rows j, pitch 17
    __shared__ float s_wfc[OUTC * 17];
    __shared__ float s_bih[3 * HC], s_bhh[3 * HC], s_bfc[OUTC], s_b2[HC];
    for (int i = threadIdx.x; i < 3 * HC * HC; i += 256)
        s_wih[(i >> 4) * 17 + (i & 15)] = w_ih[i];
    for (int i = threadIdx.x; i < OUTC * HC; i += 256)
        s_wfc[(i >> 4) * 17 + (i & 15)] = Wfc[i];
    if (threadIdx.x < 3 * HC) { s_bih[threadIdx.x] = b_ih[threadIdx.x]; s_bhh[threadIdx.x] = b_hh[threadIdx.x]; }
    if (threadIdx.x < OUTC) s_bfc[threadIdx.x] = bfc[threadIdx.x];
    if (threadIdx.x < HC) s_b2[threadIdx.x] = b2[threadIdx.x];
    __syncthreads();
    int t = blockIdx.x * blockDim.x + threadIdx.x;
    int node = t >> 4;
    if (node >= n) return;
    int f = t & 15;
    float acc = gather_row16(hd2, csr, row_beg[node], row_end[node], node, f);
    float h = fmaxf(acc * dinv[node] + s_b2[f], 0.f);
    // GRU (seq=1, h0=0 => gh = b_hh): lane f computes gate row j=f
    float ir = s_bih[f], iz = s_bih[HC + f], inn = s_bih[2 * HC + f];
#pragma unroll
    for (int k = 0; k < HC; ++k) {
        float hk = __shfl(h, k, 16);
        ir  += hk * s_wih[f * 17 + k];
        iz  += hk * s_wih[(HC + f) * 17 + k];
        inn += hk * s_wih[(2 * HC + f) * 17 + k];
    }
    float r = 1.f / (1.f + __expf(-(ir + s_bhh[f])));
    float z = 1.f / (1.f + __expf(-(iz + s_bhh[HC + f])));
    float nn = tanhf(inn + r * s_bhh[2 * HC + f]);
    float hs = (1.f - z) * nn;
    // FC: lane f computes outputs o=f and o=HC+f
    float a1 = s_bfc[f], a2 = s_bfc[HC + f];
#pragma unroll
    for (int k = 0; k < HC; ++k) {
        float hk = __shfl(hs, k, 16);
        a1 += hk * s_wfc[f * 17 + k];
        a2 += hk * s_wfc[(HC + f) * 17 + k];
    }
    float* orow = out + (size_t)node * OUTC;
    __builtin_nontemporal_store(a1, orow + f);
    __builtin_nontemporal_store(a2, orow + HC + f);
}

extern "C" void kernel_launch(void* const* d_in, const int* in_sizes, int n_in,
                              void* d_out, int out_size, void* d_ws, size_t ws_size,
                              hipStream_t stream) {
    const float* x     = (const float*)d_in[0];
    const int*   ei    = (const int*)d_in[1];
    const float* W1    = (const float*)d_in[3];
    const float* b1    = (const float*)d_in[4];
    const float* W2    = (const float*)d_in[5];
    const float* b2    = (const float*)d_in[6];
    const float* w_ih  = (const float*)d_in[7];
    // d_in[8] = w_hh unused: h0 == 0 => gh = b_hh
    const float* b_ih  = (const float*)d_in[9];
    const float* b_hh  = (const float*)d_in[10];
    const float* Wfc   = (const float*)d_in[11];
    const float* bfc   = (const float*)d_in[12];
    float* out = (float*)d_out;

    const int n = in_sizes[2];          // 200000
    const int e = in_sizes[1] / 2;      // 6400000
    const int* src = ei;
    const int* dst = ei + e;
    const int nbkt = (n + 255) >> BKT_SHIFT;   // 782

    // workspace layout (16B-aligned sections)
    int*   deg     = (int*)d_ws;                     // n
    int*   row_beg = deg + n;                        // n
    int*   row_end = row_beg + n;                    // n (doubles as scatter cursor)
    float* dinv    = (float*)(row_end + n);          // n
    int*   csrbuf  = (int*)(dinv + n);               // nbkt*CAP (28.8 MB)
    f16*   hd1     = (f16*)(csrbuf + (size_t)nbkt * CAP);  // 16n halves (6.4 MB)
    f16*   hd2     = hd1 + (size_t)n * HC;                 // 16n halves

    const int B = 256;
    int gnf = (int)(((long long)n * HC + B - 1) / B);   // 12500
    int gq  = (e / 4 + B - 1) / B;                      // quad-stride grids

    hipMemsetAsync(deg, 0, (size_t)n * sizeof(int), stream);
    degree_kernel<<<gq, B, 0, stream>>>(dst, deg, e);
    scan_gemm_kernel<<<nbkt, B, 0, stream>>>(deg, x, W1, row_beg, row_end, dinv, hd1, n);
    scatter_kernel<<<gq, B, 0, stream>>>(src, dst, row_end, csrbuf, e);
    gather_fuse1_kernel<<<gnf, B, 0, stream>>>(hd1, csrbuf, row_beg, row_end, dinv, b1, W2, hd2, n);
    gather_final_kernel<<<gnf, B, 0, stream>>>(hd2, csrbuf, row_beg, row_end, dinv, b2,
                                               w_ih, b_ih, b_hh, Wfc, bfc, out, n);
}

// Round 13
// 435.825 us; speedup vs baseline: 2.5868x; 2.5868x over previous
//
#include <hip/hip_runtime.h>
#include <hip/hip_fp16.h>
#include <math.h>

#define HC 16      // hidden
#define INC 128    // in_channels
#define OUTC 32    // out_channels
#define BKT_SHIFT 8            // 256 nodes per bucket
#define CAP 9216               // bucket edge capacity: E[8192] + 11 sigma
#define NBMAX 1024             // max buckets (782 actual)
#define BINS 12288             // 12 edges/thread * 1024 threads, exact
#define EPT 12                 // edges per thread

typedef _Float16 f16;
typedef _Float16 f16x8 __attribute__((ext_vector_type(8)));

// ================= CSR build: LDS-staged binning =================
// R12 lesson (scatter_kernel, WRITE=391MB): scattered 4B global writes do NOT
// L2-aggregate — every write evicts a dirty line. This LDS-staged design is
// what keeps CSR-build writes at 38MB. Keep it.

__global__ void init_gcur_kernel(int* __restrict__ gcur, int nbkt) {
    int i = blockIdx.x * blockDim.x + threadIdx.x;
    if (i < nbkt) gcur[i] = i * CAP;
}

// 1024 threads/block, 62KB LDS -> 2 blocks/CU = 32 waves/CU.
// Packed entry: (dlocal << 18) | src
__global__ void __launch_bounds__(1024, 8) bin_kernel(
        const int* __restrict__ src, const int* __restrict__ dst,
        int* __restrict__ gcur, int* __restrict__ csrbuf, int e, int nbkt) {
    __shared__ int ent[BINS];        // 48 KB staging
    __shared__ int hist[NBMAX];      // counts -> local cursors (reused)
    __shared__ int off[NBMAX];       // exclusive offsets into staging
    __shared__ int gbase[NBMAX];     // reserved global bases
    __shared__ int wsum[16];         // per-wave scan partials
    int tid = threadIdx.x;
    int beg = blockIdx.x * BINS;
    int end = min(beg + BINS, e);
    if (end <= beg) return;

    // phase A: load edges (statically indexed), histogram
    int myd[EPT], mys[EPT];
#pragma unroll
    for (int u = 0; u < EPT; ++u) {
        int i = beg + u * 1024 + tid;
        myd[u] = (i < end) ? dst[i] : -1;
        mys[u] = (i < end) ? src[i] : 0;
    }
    hist[tid] = 0;                   // NBMAX == blockDim
    __syncthreads();
#pragma unroll
    for (int u = 0; u < EPT; ++u)
        if (myd[u] >= 0) atomicAdd(&hist[myd[u] >> BKT_SHIFT], 1);
    __syncthreads();

    // phase B: scan, thread t owns bucket t; shfl wave-scan + 16-wave fixup
    int c = hist[tid];
    int lane = tid & 63, wid = tid >> 6;
    int v = c;
#pragma unroll
    for (int d = 1; d < 64; d <<= 1) {
        int u = __shfl_up(v, d, 64);
        if (lane >= d) v += u;
    }
    if (lane == 63) wsum[wid] = v;
    __syncthreads();
    int wbase = 0;
#pragma unroll
    for (int w = 0; w < 16; ++w) wbase += (w < wid) ? wsum[w] : 0;
    int ex = wbase + v - c;          // exclusive prefix of c
    off[tid] = ex;                   // off[nbkt] == sz (hist beyond nbkt is 0)
    if (c) gbase[tid] = atomicAdd(&gcur[tid], c);
    hist[tid] = 0;                   // reuse as cursors
    __syncthreads();

    // phase C: group into staging
#pragma unroll
    for (int u = 0; u < EPT; ++u) {
        int d = myd[u];
        if (d >= 0) {
            int b = d >> BKT_SHIFT;
            int p = off[b] + atomicAdd(&hist[b], 1);
            ent[p] = (mys[u] & 0x3FFFF) | ((d & 255) << 18);
        }
    }
    __syncthreads();

    // phase D: per-bucket flush; 16-lane group per bucket, contiguous runs
    int grp = tid >> 4;              // 64 groups
    int gl  = tid & 15;
    for (int b = grp; b < nbkt; b += 64) {
        int o = off[b];
        int cc = off[b + 1] - o;
        if (cc <= 0) continue;
        int g = gbase[b];
        for (int k = gl; k < cc; k += 16)
            csrbuf[g + k] = ent[o + k];
    }
}

// ===== bucketize + fused gemm1 (R10-proven): one block (512t) per bucket =====
__global__ void __launch_bounds__(512) bucketize_gemm_kernel(
        const int* __restrict__ gcur, int* __restrict__ csrbuf,
        const float* __restrict__ x, const float* __restrict__ W1,
        int* __restrict__ row_beg, int* __restrict__ row_end,
        float* __restrict__ dinv, f16* __restrict__ hd1, int n) {
    __shared__ int ent[CAP];     // 36 KB; reused as sW(8K)+part(17.4K) in phase 2
    __shared__ int cnt[256];
    __shared__ int off[256];
    __shared__ int cur[256];
    __shared__ int wsum2[4];
    int tid = threadIdx.x;
    int b = blockIdx.x;
    int base = b * CAP;
    int sz = gcur[b] - base;
    if (sz > CAP) sz = CAP;      // defensive (statically unreachable)
    int node0 = b << BKT_SHIFT;
    int nnodes = min(256, n - node0);
    for (int i = tid; i < sz; i += 512) ent[i] = csrbuf[base + i];
    if (tid < 256) cnt[tid] = 0;
    __syncthreads();
    for (int i = tid; i < sz; i += 512) atomicAdd(&cnt[ent[i] >> 18], 1);
    __syncthreads();
    // scan over 256 node-counts: shfl wave-scan (4 active waves) + fixup
    int v = (tid < 256) ? cnt[tid] : 0;
    int lane = tid & 63, w = tid >> 6;
    int vv = v;
#pragma unroll
    for (int d = 1; d < 64; d <<= 1) {
        int u = __shfl_up(vv, d, 64);
        if (lane >= d) vv += u;
    }
    if (tid < 256 && lane == 63) wsum2[w] = vv;
    __syncthreads();
    float di_reg = 0.f;          // this thread's node dinv (phase 2 reuse)
    if (tid < 256) {
        int wb = 0;
#pragma unroll
        for (int w2 = 0; w2 < 4; ++w2) wb += (w2 < w) ? wsum2[w2] : 0;
        int incl = wb + vv;
        int excl = incl - v;
        cur[tid] = excl;
        di_reg = rsqrtf((float)v + 1.0f);   // +1 self-loop
        if (tid < nnodes) {
            row_beg[node0 + tid] = base + excl;
            row_end[node0 + tid] = base + excl + v;
            dinv[node0 + tid] = di_reg;
        }
    }
    __syncthreads();
    for (int i = tid; i < sz; i += 512) {
        int p = ent[i];
        int dl = p >> 18;
        int pos = atomicAdd(&cur[dl], 1);
        csrbuf[base + pos] = p & 0x3FFFF;
    }
    __syncthreads();             // ent[] dead after scatter -> reuse
    // ===== phase 2: gemm1, all 512 threads (split-k by 2) =====
    float* sW   = (float*)ent;           // 2048 f32 = 8 KB
    float* part = (float*)(ent + 2048);  // 256*17 f32 = 17.4 KB
    for (int i = tid; i < INC * HC; i += 512) sW[i] = W1[i];
    __syncthreads();
    int r  = tid & 255;          // node slot
    int kh = tid >> 8;           // k-half (0: k 0..63, 1: k 64..127)
    float acc[HC];
#pragma unroll
    for (int f = 0; f < HC; ++f) acc[f] = 0.f;
    if (r < nnodes) {
        int node = node0 + r;
        const float4* xr = (const float4*)(x + (size_t)node * INC) + kh * 16;
        const float* wbase2 = &sW[kh * 64 * HC];
#pragma unroll 4
        for (int k4 = 0; k4 < 16; ++k4) {
            float4 xv = xr[k4];
            const float* wp = &wbase2[k4 * 4 * HC];
#pragma unroll
            for (int f = 0; f < HC; ++f)
                acc[f] += xv.x * wp[f] + xv.y * wp[HC + f] + xv.z * wp[2 * HC + f] + xv.w * wp[3 * HC + f];
        }
        if (kh == 1) {
#pragma unroll
            for (int f = 0; f < HC; ++f) part[r * 17 + f] = acc[f];
        }
    }
    __syncthreads();
    if (kh == 0 && r < nnodes) {
        int node = node0 + r;
        union { f16 h[HC]; float4 q[2]; } u;
#pragma unroll
        for (int f = 0; f < HC; ++f)
            u.h[f] = (f16)((acc[f] + part[r * 17 + f]) * di_reg);
        float4* hl = (float4*)(hd1 + (size_t)node * HC);
        hl[0] = u.q[0];
        hl[1] = u.q[1];
    }
}

// ===== wide-load gather core, SPLIT-PASS: two sweeps over the row by src
// range (src<split, then src>=split). Each pass's hd working set is 3.2MB ->
// fits the 4MB per-XCD L2 (hd=6.4MB alone misses ~45% to L3 at ~500cy; R12
// counters: FETCH 183MB per gather). Pass-1 csr re-read hits L1/L2 (each
// block's ~36KB bucket slab). Accumulators shared; reduce runs once.
__device__ __forceinline__ float gather_row16(
        const f16* __restrict__ hd, const int* __restrict__ csr,
        int beg, int end, int node, int f, int split) {
    int h = f & 1;           // which 16B half
    int k = f >> 1;          // edge slot 0..7
    float a0 = 0.f, a1 = 0.f, a2 = 0.f, a3 = 0.f;
    float a4 = 0.f, a5 = 0.f, a6 = 0.f, a7 = 0.f;
#pragma unroll
    for (int pass = 0; pass < 2; ++pass) {
        int jj = beg + k;
        if (jj < end) {
            int s = csr[jj];
            jj += 8;
            for (; jj < end; jj += 8) {
                int sn = csr[jj];   // prefetch next edge's src
                bool in = (pass == 0) ? (s < split) : (s >= split);
                if (in) {
                    f16x8 v = *(const f16x8*)(hd + ((size_t)s << 4) + (h << 3));
                    a0 += (float)v[0]; a1 += (float)v[1]; a2 += (float)v[2]; a3 += (float)v[3];
                    a4 += (float)v[4]; a5 += (float)v[5]; a6 += (float)v[6]; a7 += (float)v[7];
                }
                s = sn;
            }
            bool in = (pass == 0) ? (s < split) : (s >= split);
            if (in) {
                f16x8 v = *(const f16x8*)(hd + ((size_t)s << 4) + (h << 3));
                a0 += (float)v[0]; a1 += (float)v[1]; a2 += (float)v[2]; a3 += (float)v[3];
                a4 += (float)v[4]; a5 += (float)v[5]; a6 += (float)v[6]; a7 += (float)v[7];
            }
        }
    }
    // reduce across the 8 lanes sharing this half (xor over slot bits = lane bits 1..3)
#pragma unroll
    for (int m = 2; m <= 8; m <<= 1) {
        a0 += __shfl_xor(a0, m, 16); a1 += __shfl_xor(a1, m, 16);
        a2 += __shfl_xor(a2, m, 16); a3 += __shfl_xor(a3, m, 16);
        a4 += __shfl_xor(a4, m, 16); a5 += __shfl_xor(a5, m, 16);
        a6 += __shfl_xor(a6, m, 16); a7 += __shfl_xor(a7, m, 16);
    }
    // rearrange to "lane f holds feature f". Source-side select: lane l exports
    // element (l>>1)=k of its half (l&1)=h, i.e. feature (h*8 + k). Destination f
    // needs half f>>3, element f&7 -> source lane ((f&7)<<1)|(f>>3).
    float e = a0;
    e = (k == 1) ? a1 : e;
    e = (k == 2) ? a2 : e;
    e = (k == 3) ? a3 : e;
    e = (k == 4) ? a4 : e;
    e = (k == 5) ? a5 : e;
    e = (k == 6) ? a6 : e;
    e = (k == 7) ? a7 : e;
    float gsum = __shfl(e, ((f & 7) << 1) | (f >> 3), 16);
    // self-loop term
    return gsum + (float)hd[(size_t)node * HC + f];
}

// ===== layer-1 gather + fused W2 =====
__global__ void __launch_bounds__(256) gather_fuse1_kernel(
        const f16* __restrict__ hd1, const int* __restrict__ csr,
        const int* __restrict__ row_beg, const int* __restrict__ row_end,
        const float* __restrict__ dinv, const float* __restrict__ b1,
        const float* __restrict__ W2, f16* __restrict__ hd2, int n, int split) {
    __shared__ float sW[HC * 17];    // pitch 17: conflict-free column reads
    __shared__ float sb[HC];
    if (threadIdx.x < HC * HC) sW[(threadIdx.x >> 4) * 17 + (threadIdx.x & 15)] = W2[threadIdx.x];
    if (threadIdx.x < HC) sb[threadIdx.x] = b1[threadIdx.x];
    __syncthreads();
    int t = blockIdx.x * blockDim.x + threadIdx.x;
    int node = t >> 4;
    if (node >= n) return;
    int f = t & 15;
    float acc = gather_row16(hd1, csr, row_beg[node], row_end[node], node, f, split);
    float di = dinv[node];
    float h1 = fmaxf(acc * di + sb[f], 0.f);
    float a2 = 0.f;
#pragma unroll
    for (int k = 0; k < HC; ++k) {
        float hk = __shfl(h1, k, 16);
        a2 += hk * sW[k * 17 + f];
    }
    hd2[(size_t)node * HC + f] = (f16)(a2 * di);
}

// ===== layer-2 gather + fused GRU + FC =====
__global__ void __launch_bounds__(256) gather_final_kernel(
        const f16* __restrict__ hd2, const int* __restrict__ csr,
        const int* __restrict__ row_beg, const int* __restrict__ row_end,
        const float* __restrict__ dinv, const float* __restrict__ b2,
        const float* __restrict__ w_ih, const float* __restrict__ b_ih,
        const float* __restrict__ b_hh, const float* __restrict__ Wfc,
        const float* __restrict__ bfc, float* __restrict__ out, int n, int split) {
    __shared__ float s_wih[3 * HC * 17];   // rows j, pitch 17
    __shared__ float s_wfc[OUTC * 17];
    __shared__ float s_bih[3 * HC], s_bhh[3 * HC], s_bfc[OUTC], s_b2[HC];
    for (int i = threadIdx.x; i < 3 * HC * HC; i += 256)
        s_wih[(i >> 4) * 17 + (i & 15)] = w_ih[i];
    for (int i = threadIdx.x; i < OUTC * HC; i += 256)
        s_wfc[(i >> 4) * 17 + (i & 15)] = Wfc[i];
    if (threadIdx.x < 3 * HC) { s_bih[threadIdx.x] = b_ih[threadIdx.x]; s_bhh[threadIdx.x] = b_hh[threadIdx.x]; }
    if (threadIdx.x < OUTC) s_bfc[threadIdx.x] = bfc[threadIdx.x];
    if (threadIdx.x < HC) s_b2[threadIdx.x] = b2[threadIdx.x];
    __syncthreads();
    int t = blockIdx.x * blockDim.x + threadIdx.x;
    int node = t >> 4;
    if (node >= n) return;
    int f = t & 15;
    float acc = gather_row16(hd2, csr, row_beg[node], row_end[node], node, f, split);
    float h = fmaxf(acc * dinv[node] + s_b2[f], 0.f);
    // GRU (seq=1, h0=0 => gh = b_hh): lane f computes gate row j=f
    float ir = s_bih[f], iz = s_bih[HC + f], inn = s_bih[2 * HC + f];
#pragma unroll
    for (int k = 0; k < HC; ++k) {
        float hk = __shfl(h, k, 16);
        ir  += hk * s_wih[f * 17 + k];
        iz  += hk * s_wih[(HC + f) * 17 + k];
        inn += hk * s_wih[(2 * HC + f) * 17 + k];
    }
    float r = 1.f / (1.f + __expf(-(ir + s_bhh[f])));
    float z = 1.f / (1.f + __expf(-(iz + s_bhh[HC + f])));
    float nn = tanhf(inn + r * s_bhh[2 * HC + f]);
    float hs = (1.f - z) * nn;
    // FC: lane f computes outputs o=f and o=HC+f
    float a1 = s_bfc[f], a2 = s_bfc[HC + f];
#pragma unroll
    for (int k = 0; k < HC; ++k) {
        float hk = __shfl(hs, k, 16);
        a1 += hk * s_wfc[f * 17 + k];
        a2 += hk * s_wfc[(HC + f) * 17 + k];
    }
    float* orow = out + (size_t)node * OUTC;
    __builtin_nontemporal_store(a1, orow + f);
    __builtin_nontemporal_store(a2, orow + HC + f);
}

extern "C" void kernel_launch(void* const* d_in, const int* in_sizes, int n_in,
                              void* d_out, int out_size, void* d_ws, size_t ws_size,
                              hipStream_t stream) {
    const float* x     = (const float*)d_in[0];
    const int*   ei    = (const int*)d_in[1];
    const float* W1    = (const float*)d_in[3];
    const float* b1    = (const float*)d_in[4];
    const float* W2    = (const float*)d_in[5];
    const float* b2    = (const float*)d_in[6];
    const float* w_ih  = (const float*)d_in[7];
    // d_in[8] = w_hh unused: h0 == 0 => gh = b_hh
    const float* b_ih  = (const float*)d_in[9];
    const float* b_hh  = (const float*)d_in[10];
    const float* Wfc   = (const float*)d_in[11];
    const float* bfc   = (const float*)d_in[12];
    float* out = (float*)d_out;

    const int n = in_sizes[2];          // 200000
    const int e = in_sizes[1] / 2;      // 6400000
    const int* src = ei;
    const int* dst = ei + e;
    const int nbkt = (n + 255) >> BKT_SHIFT;   // 782
    const int split = n >> 1;                  // src-range split for L2-resident gather passes

    // workspace layout (16B-aligned sections)
    int*   gcur    = (int*)d_ws;                     // 1024
    int*   row_beg = gcur + 1024;                    // n
    int*   row_end = row_beg + n;                    // n
    float* dinv    = (float*)(row_end + n);          // n
    int*   csrbuf  = (int*)(dinv + n);               // nbkt*CAP
    f16*   hd1     = (f16*)(csrbuf + (size_t)nbkt * CAP);  // 16n halves (6.4 MB)
    f16*   hd2     = hd1 + (size_t)n * HC;                 // 16n halves

    const int B = 256;
    int gnf  = (int)(((long long)n * HC + B - 1) / B);  // 12500
    int gbin = (e + BINS - 1) / BINS;                   // 521

    init_gcur_kernel<<<(NBMAX + B - 1) / B, B, 0, stream>>>(gcur, nbkt);
    bin_kernel<<<gbin, 1024, 0, stream>>>(src, dst, gcur, csrbuf, e, nbkt);
    bucketize_gemm_kernel<<<nbkt, 512, 0, stream>>>(gcur, csrbuf, x, W1,
                                                    row_beg, row_end, dinv, hd1, n);
    gather_fuse1_kernel<<<gnf, B, 0, stream>>>(hd1, csrbuf, row_beg, row_end, dinv, b1, W2, hd2, n, split);
    gather_final_kernel<<<gnf, B, 0, stream>>>(hd2, csrbuf, row_beg, row_end, dinv, b2,
                                               w_ih, b_ih, b_hh, Wfc, bfc, out, n, split);
}

// Round 14
// 396.780 us; speedup vs baseline: 2.8414x; 1.0984x over previous
//
#include <hip/hip_runtime.h>
#include <hip/hip_fp16.h>
#include <hip/hip_fp8.h>
#include <math.h>

#define HC 16      // hidden
#define INC 128    // in_channels
#define OUTC 32    // out_channels
#define BKT_SHIFT 8            // 256 nodes per bucket
#define CAP 9216               // bucket edge capacity: E[8192] + 11 sigma
#define NBMAX 1024             // max buckets (782 actual)
#define BINS 12288             // 12 edges/thread * 1024 threads, exact
#define EPT 12                 // edges per thread

typedef _Float16 f16;
typedef _Float16 f16x8 __attribute__((ext_vector_type(8)));
typedef float vf2 __attribute__((ext_vector_type(2)));

// ===== fp8 e4m3 (OCP) helpers: HW cvt builtins with header fallback =====
__device__ __forceinline__ void acc4_fp8(unsigned int w,
        float& a, float& b, float& c, float& d) {
#if __has_builtin(__builtin_amdgcn_cvt_pk_f32_fp8)
    vf2 lo = __builtin_amdgcn_cvt_pk_f32_fp8(w, false);
    vf2 hi = __builtin_amdgcn_cvt_pk_f32_fp8(w, true);
    a += lo[0]; b += lo[1]; c += hi[0]; d += hi[1];
#else
    __hip_fp8_e4m3 t;
    t.__x = w & 0xFF;         a += (float)t;
    t.__x = (w >> 8) & 0xFF;  b += (float)t;
    t.__x = (w >> 16) & 0xFF; c += (float)t;
    t.__x = (w >> 24) & 0xFF; d += (float)t;
#endif
}

__device__ __forceinline__ float fp8_to_f(unsigned char b) {
#if __has_builtin(__builtin_amdgcn_cvt_f32_fp8)
    return __builtin_amdgcn_cvt_f32_fp8((int)b, 0);
#else
    __hip_fp8_e4m3 t; t.__x = b; return (float)t;
#endif
}

__device__ __forceinline__ int pack4_fp8(float a, float b, float c, float d) {
#if __has_builtin(__builtin_amdgcn_cvt_pk_fp8_f32)
    int w = __builtin_amdgcn_cvt_pk_fp8_f32(a, b, 0, false);
    w = __builtin_amdgcn_cvt_pk_fp8_f32(c, d, w, true);
    return w;
#else
    __hip_fp8_e4m3 q0(a), q1(b), q2(c), q3(d);
    return (int)q0.__x | ((int)q1.__x << 8) | ((int)q2.__x << 16) | ((int)q3.__x << 24);
#endif
}

// ================= CSR build: LDS-staged binning =================
// R12 lesson: scattered 4B global writes do NOT L2-aggregate (WRITE=391MB).
// This LDS-staged design keeps CSR-build writes at ~38MB. Keep it.

__global__ void init_gcur_kernel(int* __restrict__ gcur, int nbkt) {
    int i = blockIdx.x * blockDim.x + threadIdx.x;
    if (i < nbkt) gcur[i] = i * CAP;
}

// 1024 threads/block, 62KB LDS -> 2 blocks/CU = 32 waves/CU.
// Packed entry: (dlocal << 18) | src
__global__ void __launch_bounds__(1024, 8) bin_kernel(
        const int* __restrict__ src, const int* __restrict__ dst,
        int* __restrict__ gcur, int* __restrict__ csrbuf, int e, int nbkt) {
    __shared__ int ent[BINS];        // 48 KB staging
    __shared__ int hist[NBMAX];      // counts -> local cursors (reused)
    __shared__ int off[NBMAX];       // exclusive offsets into staging
    __shared__ int gbase[NBMAX];     // reserved global bases
    __shared__ int wsum[16];         // per-wave scan partials
    int tid = threadIdx.x;
    int beg = blockIdx.x * BINS;
    int end = min(beg + BINS, e);
    if (end <= beg) return;

    // phase A: load edges (statically indexed), histogram
    int myd[EPT], mys[EPT];
#pragma unroll
    for (int u = 0; u < EPT; ++u) {
        int i = beg + u * 1024 + tid;
        myd[u] = (i < end) ? dst[i] : -1;
        mys[u] = (i < end) ? src[i] : 0;
    }
    hist[tid] = 0;                   // NBMAX == blockDim
    __syncthreads();
#pragma unroll
    for (int u = 0; u < EPT; ++u)
        if (myd[u] >= 0) atomicAdd(&hist[myd[u] >> BKT_SHIFT], 1);
    __syncthreads();

    // phase B: scan, thread t owns bucket t; shfl wave-scan + 16-wave fixup
    int c = hist[tid];
    int lane = tid & 63, wid = tid >> 6;
    int v = c;
#pragma unroll
    for (int d = 1; d < 64; d <<= 1) {
        int u = __shfl_up(v, d, 64);
        if (lane >= d) v += u;
    }
    if (lane == 63) wsum[wid] = v;
    __syncthreads();
    int wbase = 0;
#pragma unroll
    for (int w = 0; w < 16; ++w) wbase += (w < wid) ? wsum[w] : 0;
    int ex = wbase + v - c;          // exclusive prefix of c
    off[tid] = ex;                   // off[nbkt] == sz (hist beyond nbkt is 0)
    if (c) gbase[tid] = atomicAdd(&gcur[tid], c);
    hist[tid] = 0;                   // reuse as cursors
    __syncthreads();

    // phase C: group into staging
#pragma unroll
    for (int u = 0; u < EPT; ++u) {
        int d = myd[u];
        if (d >= 0) {
            int b = d >> BKT_SHIFT;
            int p = off[b] + atomicAdd(&hist[b], 1);
            ent[p] = (mys[u] & 0x3FFFF) | ((d & 255) << 18);
        }
    }
    __syncthreads();

    // phase D: per-bucket flush; 16-lane group per bucket, contiguous runs
    int grp = tid >> 4;              // 64 groups
    int gl  = tid & 15;
    for (int b = grp; b < nbkt; b += 64) {
        int o = off[b];
        int cc = off[b + 1] - o;
        if (cc <= 0) continue;
        int g = gbase[b];
        for (int k = gl; k < cc; k += 16)
            csrbuf[g + k] = ent[o + k];
    }
}

// ===== bucketize + fused gemm1 (R10-proven): one block (512t) per bucket =====
// hd1 is now fp8 e4m3 (16B/row, 3.2MB table -> fits 4MB per-XCD L2).
__global__ void __launch_bounds__(512) bucketize_gemm_kernel(
        const int* __restrict__ gcur, int* __restrict__ csrbuf,
        const float* __restrict__ x, const float* __restrict__ W1,
        int* __restrict__ row_beg, int* __restrict__ row_end,
        float* __restrict__ dinv, unsigned char* __restrict__ hd1, int n) {
    __shared__ int ent[CAP];     // 36 KB; reused as sW(8K)+part(17.4K) in phase 2
    __shared__ int cnt[256];
    __shared__ int off[256];
    __shared__ int cur[256];
    __shared__ int wsum2[4];
    int tid = threadIdx.x;
    int b = blockIdx.x;
    int base = b * CAP;
    int sz = gcur[b] - base;
    if (sz > CAP) sz = CAP;      // defensive (statically unreachable)
    int node0 = b << BKT_SHIFT;
    int nnodes = min(256, n - node0);
    for (int i = tid; i < sz; i += 512) ent[i] = csrbuf[base + i];
    if (tid < 256) cnt[tid] = 0;
    __syncthreads();
    for (int i = tid; i < sz; i += 512) atomicAdd(&cnt[ent[i] >> 18], 1);
    __syncthreads();
    // scan over 256 node-counts: shfl wave-scan (4 active waves) + fixup
    int v = (tid < 256) ? cnt[tid] : 0;
    int lane = tid & 63, w = tid >> 6;
    int vv = v;
#pragma unroll
    for (int d = 1; d < 64; d <<= 1) {
        int u = __shfl_up(vv, d, 64);
        if (lane >= d) vv += u;
    }
    if (tid < 256 && lane == 63) wsum2[w] = vv;
    __syncthreads();
    float di_reg = 0.f;          // this thread's node dinv (phase 2 reuse)
    if (tid < 256) {
        int wb = 0;
#pragma unroll
        for (int w2 = 0; w2 < 4; ++w2) wb += (w2 < w) ? wsum2[w2] : 0;
        int incl = wb + vv;
        int excl = incl - v;
        cur[tid] = excl;
        di_reg = rsqrtf((float)v + 1.0f);   // +1 self-loop
        if (tid < nnodes) {
            row_beg[node0 + tid] = base + excl;
            row_end[node0 + tid] = base + excl + v;
            dinv[node0 + tid] = di_reg;
        }
    }
    __syncthreads();
    for (int i = tid; i < sz; i += 512) {
        int p = ent[i];
        int dl = p >> 18;
        int pos = atomicAdd(&cur[dl], 1);
        csrbuf[base + pos] = p & 0x3FFFF;
    }
    __syncthreads();             // ent[] dead after scatter -> reuse
    // ===== phase 2: gemm1, all 512 threads (split-k by 2) =====
    float* sW   = (float*)ent;           // 2048 f32 = 8 KB
    float* part = (float*)(ent + 2048);  // 256*17 f32 = 17.4 KB
    for (int i = tid; i < INC * HC; i += 512) sW[i] = W1[i];
    __syncthreads();
    int r  = tid & 255;          // node slot
    int kh = tid >> 8;           // k-half (0: k 0..63, 1: k 64..127)
    float acc[HC];
#pragma unroll
    for (int f = 0; f < HC; ++f) acc[f] = 0.f;
    if (r < nnodes) {
        int node = node0 + r;
        const float4* xr = (const float4*)(x + (size_t)node * INC) + kh * 16;
        const float* wbase2 = &sW[kh * 64 * HC];
#pragma unroll 4
        for (int k4 = 0; k4 < 16; ++k4) {
            float4 xv = xr[k4];
            const float* wp = &wbase2[k4 * 4 * HC];
#pragma unroll
            for (int f = 0; f < HC; ++f)
                acc[f] += xv.x * wp[f] + xv.y * wp[HC + f] + xv.z * wp[2 * HC + f] + xv.w * wp[3 * HC + f];
        }
        if (kh == 1) {
#pragma unroll
            for (int f = 0; f < HC; ++f) part[r * 17 + f] = acc[f];
        }
    }
    __syncthreads();
    if (kh == 0 && r < nnodes) {
        int node = node0 + r;
        float t[HC];
#pragma unroll
        for (int f = 0; f < HC; ++f) t[f] = (acc[f] + part[r * 17 + f]) * di_reg;
        int4 st;
        st.x = pack4_fp8(t[0],  t[1],  t[2],  t[3]);
        st.y = pack4_fp8(t[4],  t[5],  t[6],  t[7]);
        st.z = pack4_fp8(t[8],  t[9],  t[10], t[11]);
        st.w = pack4_fp8(t[12], t[13], t[14], t[15]);
        *(int4*)(hd1 + (size_t)node * 16) = st;
    }
}

// ===== wide-load gather core (fp16 rows, 32B): lane l of 16-lane group =
// (half h=l&1, slot k=l>>1); each lane strides edges by 8 loading 16B.
__device__ __forceinline__ float gather_row16(
        const f16* __restrict__ hd, const int* __restrict__ csr,
        int beg, int end, int node, int f) {
    int h = f & 1;           // which 16B half
    int k = f >> 1;          // edge slot 0..7
    float a0 = 0.f, a1 = 0.f, a2 = 0.f, a3 = 0.f;
    float a4 = 0.f, a5 = 0.f, a6 = 0.f, a7 = 0.f;
    int jj = beg + k;
    if (jj < end) {
        int s = csr[jj];
        jj += 8;
        for (; jj < end; jj += 8) {
            int sn = csr[jj];   // prefetch next edge's src (hides csr latency)
            f16x8 v = *(const f16x8*)(hd + ((size_t)s << 4) + (h << 3));
            a0 += (float)v[0]; a1 += (float)v[1]; a2 += (float)v[2]; a3 += (float)v[3];
            a4 += (float)v[4]; a5 += (float)v[5]; a6 += (float)v[6]; a7 += (float)v[7];
            s = sn;
        }
        f16x8 v = *(const f16x8*)(hd + ((size_t)s << 4) + (h << 3));
        a0 += (float)v[0]; a1 += (float)v[1]; a2 += (float)v[2]; a3 += (float)v[3];
        a4 += (float)v[4]; a5 += (float)v[5]; a6 += (float)v[6]; a7 += (float)v[7];
    }
#pragma unroll
    for (int m = 2; m <= 8; m <<= 1) {
        a0 += __shfl_xor(a0, m, 16); a1 += __shfl_xor(a1, m, 16);
        a2 += __shfl_xor(a2, m, 16); a3 += __shfl_xor(a3, m, 16);
        a4 += __shfl_xor(a4, m, 16); a5 += __shfl_xor(a5, m, 16);
        a6 += __shfl_xor(a6, m, 16); a7 += __shfl_xor(a7, m, 16);
    }
    // lane l exports element (l>>1)=k of half (l&1)=h = feature h*8+k;
    // dest f pulls from lane ((f&7)<<1)|(f>>3).
    float e = a0;
    e = (k == 1) ? a1 : e;
    e = (k == 2) ? a2 : e;
    e = (k == 3) ? a3 : e;
    e = (k == 4) ? a4 : e;
    e = (k == 5) ? a5 : e;
    e = (k == 6) ? a6 : e;
    e = (k == 7) ? a7 : e;
    float gsum = __shfl(e, ((f & 7) << 1) | (f >> 3), 16);
    return gsum + (float)hd[(size_t)node * HC + f];
}

// ===== fp8 variant (hd rows 16B): lane loads 8B (uint2) per edge =====
__device__ __forceinline__ float gather_row16_f8(
        const unsigned char* __restrict__ hd, const int* __restrict__ csr,
        int beg, int end, int node, int f) {
    int h = f & 1;           // which 8B half
    int k = f >> 1;          // edge slot 0..7
    float a0 = 0.f, a1 = 0.f, a2 = 0.f, a3 = 0.f;
    float a4 = 0.f, a5 = 0.f, a6 = 0.f, a7 = 0.f;
    int jj = beg + k;
    if (jj < end) {
        int s = csr[jj];
        jj += 8;
        for (; jj < end; jj += 8) {
            int sn = csr[jj];
            uint2 v = *(const uint2*)(hd + ((size_t)s << 4) + (h << 3));
            acc4_fp8(v.x, a0, a1, a2, a3);
            acc4_fp8(v.y, a4, a5, a6, a7);
            s = sn;
        }
        uint2 v = *(const uint2*)(hd + ((size_t)s << 4) + (h << 3));
        acc4_fp8(v.x, a0, a1, a2, a3);
        acc4_fp8(v.y, a4, a5, a6, a7);
    }
#pragma unroll
    for (int m = 2; m <= 8; m <<= 1) {
        a0 += __shfl_xor(a0, m, 16); a1 += __shfl_xor(a1, m, 16);
        a2 += __shfl_xor(a2, m, 16); a3 += __shfl_xor(a3, m, 16);
        a4 += __shfl_xor(a4, m, 16); a5 += __shfl_xor(a5, m, 16);
        a6 += __shfl_xor(a6, m, 16); a7 += __shfl_xor(a7, m, 16);
    }
    float e = a0;
    e = (k == 1) ? a1 : e;
    e = (k == 2) ? a2 : e;
    e = (k == 3) ? a3 : e;
    e = (k == 4) ? a4 : e;
    e = (k == 5) ? a5 : e;
    e = (k == 6) ? a6 : e;
    e = (k == 7) ? a7 : e;
    float gsum = __shfl(e, ((f & 7) << 1) | (f >> 3), 16);
    return gsum + fp8_to_f(hd[(size_t)node * 16 + f]);
}

// ===== layer-1 gather (fp8 hd1) + fused W2; hd2 stays fp16 =====
__global__ void __launch_bounds__(256) gather_fuse1_kernel(
        const unsigned char* __restrict__ hd1, const int* __restrict__ csr,
        const int* __restrict__ row_beg, const int* __restrict__ row_end,
        const float* __restrict__ dinv, const float* __restrict__ b1,
        const float* __restrict__ W2, f16* __restrict__ hd2, int n) {
    __shared__ float sW[HC * 17];    // pitch 17: conflict-free column reads
    __shared__ float sb[HC];
    if (threadIdx.x < HC * HC) sW[(threadIdx.x >> 4) * 17 + (threadIdx.x & 15)] = W2[threadIdx.x];
    if (threadIdx.x < HC) sb[threadIdx.x] = b1[threadIdx.x];
    __syncthreads();
    int t = blockIdx.x * blockDim.x + threadIdx.x;
    int node = t >> 4;
    if (node >= n) return;
    int f = t & 15;
    float acc = gather_row16_f8(hd1, csr, row_beg[node], row_end[node], node, f);
    float di = dinv[node];
    float h1 = fmaxf(acc * di + sb[f], 0.f);
    float a2 = 0.f;
#pragma unroll
    for (int k = 0; k < HC; ++k) {
        float hk = __shfl(h1, k, 16);
        a2 += hk * sW[k * 17 + f];
    }
    hd2[(size_t)node * HC + f] = (f16)(a2 * di);
}

// ===== layer-2 gather + fused GRU + FC =====
__global__ void __launch_bounds__(256) gather_final_kernel(
        const f16* __restrict__ hd2, const int* __restrict__ csr,
        const int* __restrict__ row_beg, const int* __restrict__ row_end,
        const float* __restrict__ dinv, const float* __restrict__ b2,
        const float* __restrict__ w_ih, const float* __restrict__ b_ih,
        const float* __restrict__ b_hh, const float* __restrict__ Wfc,
        const float* __restrict__ bfc, float* __restrict__ out, int n) {
    __shared__ float s_wih[3 * HC * 17];   // rows j, pitch 17
    __shared__ float s_wfc[OUTC * 17];
    __shared__ float s_bih[3 * HC], s_bhh[3 * HC], s_bfc[OUTC], s_b2[HC];
    for (int i = threadIdx.x; i < 3 * HC * HC; i += 256)
        s_wih[(i >> 4) * 17 + (i & 15)] = w_ih[i];
    for (int i = threadIdx.x; i < OUTC * HC; i += 256)
        s_wfc[(i >> 4) * 17 + (i & 15)] = Wfc[i];
    if (threadIdx.x < 3 * HC) { s_bih[threadIdx.x] = b_ih[threadIdx.x]; s_bhh[threadIdx.x] = b_hh[threadIdx.x]; }
    if (threadIdx.x < OUTC) s_bfc[threadIdx.x] = bfc[threadIdx.x];
    if (threadIdx.x < HC) s_b2[threadIdx.x] = b2[threadIdx.x];
    __syncthreads();
    int t = blockIdx.x * blockDim.x + threadIdx.x;
    int node = t >> 4;
    if (node >= n) return;
    int f = t & 15;
    float acc = gather_row16(hd2, csr, row_beg[node], row_end[node], node, f);
    float h = fmaxf(acc * dinv[node] + s_b2[f], 0.f);
    // GRU (seq=1, h0=0 => gh = b_hh): lane f computes gate row j=f
    float ir = s_bih[f], iz = s_bih[HC + f], inn = s_bih[2 * HC + f];
#pragma unroll
    for (int k = 0; k < HC; ++k) {
        float hk = __shfl(h, k, 16);
        ir  += hk * s_wih[f * 17 + k];
        iz  += hk * s_wih[(HC + f) * 17 + k];
        inn += hk * s_wih[(2 * HC + f) * 17 + k];
    }
    float r = 1.f / (1.f + __expf(-(ir + s_bhh[f])));
    float z = 1.f / (1.f + __expf(-(iz + s_bhh[HC + f])));
    float nn = tanhf(inn + r * s_bhh[2 * HC + f]);
    float hs = (1.f - z) * nn;
    // FC: lane f computes outputs o=f and o=HC+f
    float a1 = s_bfc[f], a2 = s_bfc[HC + f];
#pragma unroll
    for (int k = 0; k < HC; ++k) {
        float hk = __shfl(hs, k, 16);
        a1 += hk * s_wfc[f * 17 + k];
        a2 += hk * s_wfc[(HC + f) * 17 + k];
    }
    float* orow = out + (size_t)node * OUTC;
    __builtin_nontemporal_store(a1, orow + f);
    __builtin_nontemporal_store(a2, orow + HC + f);
}

extern "C" void kernel_launch(void* const* d_in, const int* in_sizes, int n_in,
                              void* d_out, int out_size, void* d_ws, size_t ws_size,
                              hipStream_t stream) {
    const float* x     = (const float*)d_in[0];
    const int*   ei    = (const int*)d_in[1];
    const float* W1    = (const float*)d_in[3];
    const float* b1    = (const float*)d_in[4];
    const float* W2    = (const float*)d_in[5];
    const float* b2    = (const float*)d_in[6];
    const float* w_ih  = (const float*)d_in[7];
    // d_in[8] = w_hh unused: h0 == 0 => gh = b_hh
    const float* b_ih  = (const float*)d_in[9];
    const float* b_hh  = (const float*)d_in[10];
    const float* Wfc   = (const float*)d_in[11];
    const float* bfc   = (const float*)d_in[12];
    float* out = (float*)d_out;

    const int n = in_sizes[2];          // 200000
    const int e = in_sizes[1] / 2;      // 6400000
    const int* src = ei;
    const int* dst = ei + e;
    const int nbkt = (n + 255) >> BKT_SHIFT;   // 782

    // workspace layout (16B-aligned sections)
    int*   gcur    = (int*)d_ws;                     // 1024
    int*   row_beg = gcur + 1024;                    // n
    int*   row_end = row_beg + n;                    // n
    float* dinv    = (float*)(row_end + n);          // n
    int*   csrbuf  = (int*)(dinv + n);               // nbkt*CAP
    unsigned char* hd1 = (unsigned char*)(csrbuf + (size_t)nbkt * CAP);  // 16n bytes (3.2 MB, fp8)
    f16*   hd2     = (f16*)(hd1 + (size_t)n * 16);   // 16n halves (6.4 MB, fp16)

    const int B = 256;
    int gnf  = (int)(((long long)n * HC + B - 1) / B);  // 12500
    int gbin = (e + BINS - 1) / BINS;                   // 521

    init_gcur_kernel<<<(NBMAX + B - 1) / B, B, 0, stream>>>(gcur, nbkt);
    bin_kernel<<<gbin, 1024, 0, stream>>>(src, dst, gcur, csrbuf, e, nbkt);
    bucketize_gemm_kernel<<<nbkt, 512, 0, stream>>>(gcur, csrbuf, x, W1,
                                                    row_beg, row_end, dinv, hd1, n);
    gather_fuse1_kernel<<<gnf, B, 0, stream>>>(hd1, csrbuf, row_beg, row_end, dinv, b1, W2, hd2, n);
    gather_final_kernel<<<gnf, B, 0, stream>>>(hd2, csrbuf, row_beg, row_end, dinv, b2,
                                               w_ih, b_ih, b_hh, Wfc, bfc, out, n);
}

// Round 15
// 390.779 us; speedup vs baseline: 2.8850x; 1.0154x over previous
//
#include <hip/hip_runtime.h>
#include <hip/hip_fp16.h>
#include <hip/hip_fp8.h>
#include <math.h>

#define HC 16      // hidden
#define INC 128    // in_channels
#define OUTC 32    // out_channels
#define BKT_SHIFT 8            // 256 nodes per bucket
#define CAP 9216               // bucket edge capacity: E[8192] + 11 sigma
#define NBMAX 1024             // max buckets (782 actual)
#define BINS 12288             // 12 edges/thread * 1024 threads, exact
#define EPT 12                 // edges per thread

typedef _Float16 f16;
typedef float vf2 __attribute__((ext_vector_type(2)));

// ===== fp8 e4m3 (OCP) helpers: HW cvt builtins with header fallback =====
__device__ __forceinline__ void acc4_fp8(unsigned int w,
        float& a, float& b, float& c, float& d) {
#if __has_builtin(__builtin_amdgcn_cvt_pk_f32_fp8)
    vf2 lo = __builtin_amdgcn_cvt_pk_f32_fp8(w, false);
    vf2 hi = __builtin_amdgcn_cvt_pk_f32_fp8(w, true);
    a += lo[0]; b += lo[1]; c += hi[0]; d += hi[1];
#else
    __hip_fp8_e4m3 t;
    t.__x = w & 0xFF;         a += (float)t;
    t.__x = (w >> 8) & 0xFF;  b += (float)t;
    t.__x = (w >> 16) & 0xFF; c += (float)t;
    t.__x = (w >> 24) & 0xFF; d += (float)t;
#endif
}

__device__ __forceinline__ float fp8_to_f(unsigned char b) {
#if __has_builtin(__builtin_amdgcn_cvt_f32_fp8)
    return __builtin_amdgcn_cvt_f32_fp8((int)b, 0);
#else
    __hip_fp8_e4m3 t; t.__x = b; return (float)t;
#endif
}

__device__ __forceinline__ int pack4_fp8(float a, float b, float c, float d) {
#if __has_builtin(__builtin_amdgcn_cvt_pk_fp8_f32)
    int w = __builtin_amdgcn_cvt_pk_fp8_f32(a, b, 0, false);
    w = __builtin_amdgcn_cvt_pk_fp8_f32(c, d, w, true);
    return w;
#else
    __hip_fp8_e4m3 q0(a), q1(b), q2(c), q3(d);
    return (int)q0.__x | ((int)q1.__x << 8) | ((int)q2.__x << 16) | ((int)q3.__x << 24);
#endif
}

__device__ __forceinline__ unsigned char f_to_fp8(float a) {
#if __has_builtin(__builtin_amdgcn_cvt_pk_fp8_f32)
    int w = __builtin_amdgcn_cvt_pk_fp8_f32(a, a, 0, false);
    return (unsigned char)(w & 0xFF);
#else
    __hip_fp8_e4m3 q(a); return q.__x;
#endif
}

// ================= CSR build: LDS-staged binning =================
// R12 lesson: scattered 4B global writes do NOT L2-aggregate (WRITE=391MB).
// This LDS-staged design keeps CSR-build writes at ~38MB. Keep it.

__global__ void init_gcur_kernel(int* __restrict__ gcur, int nbkt) {
    int i = blockIdx.x * blockDim.x + threadIdx.x;
    if (i < nbkt) gcur[i] = i * CAP;
}

// 1024 threads/block, 62KB LDS -> 2 blocks/CU = 32 waves/CU.
// Packed entry: (dlocal << 18) | src
__global__ void __launch_bounds__(1024, 8) bin_kernel(
        const int* __restrict__ src, const int* __restrict__ dst,
        int* __restrict__ gcur, int* __restrict__ csrbuf, int e, int nbkt) {
    __shared__ int ent[BINS];        // 48 KB staging
    __shared__ int hist[NBMAX];      // counts -> local cursors (reused)
    __shared__ int off[NBMAX];       // exclusive offsets into staging
    __shared__ int gbase[NBMAX];     // reserved global bases
    __shared__ int wsum[16];         // per-wave scan partials
    int tid = threadIdx.x;
    int beg = blockIdx.x * BINS;
    int end = min(beg + BINS, e);
    if (end <= beg) return;

    // phase A: load edges (statically indexed), histogram
    int myd[EPT], mys[EPT];
#pragma unroll
    for (int u = 0; u < EPT; ++u) {
        int i = beg + u * 1024 + tid;
        myd[u] = (i < end) ? dst[i] : -1;
        mys[u] = (i < end) ? src[i] : 0;
    }
    hist[tid] = 0;                   // NBMAX == blockDim
    __syncthreads();
#pragma unroll
    for (int u = 0; u < EPT; ++u)
        if (myd[u] >= 0) atomicAdd(&hist[myd[u] >> BKT_SHIFT], 1);
    __syncthreads();

    // phase B: scan, thread t owns bucket t; shfl wave-scan + 16-wave fixup
    int c = hist[tid];
    int lane = tid & 63, wid = tid >> 6;
    int v = c;
#pragma unroll
    for (int d = 1; d < 64; d <<= 1) {
        int u = __shfl_up(v, d, 64);
        if (lane >= d) v += u;
    }
    if (lane == 63) wsum[wid] = v;
    __syncthreads();
    int wbase = 0;
#pragma unroll
    for (int w = 0; w < 16; ++w) wbase += (w < wid) ? wsum[w] : 0;
    int ex = wbase + v - c;          // exclusive prefix of c
    off[tid] = ex;                   // off[nbkt] == sz (hist beyond nbkt is 0)
    if (c) gbase[tid] = atomicAdd(&gcur[tid], c);
    hist[tid] = 0;                   // reuse as cursors
    __syncthreads();

    // phase C: group into staging
#pragma unroll
    for (int u = 0; u < EPT; ++u) {
        int d = myd[u];
        if (d >= 0) {
            int b = d >> BKT_SHIFT;
            int p = off[b] + atomicAdd(&hist[b], 1);
            ent[p] = (mys[u] & 0x3FFFF) | ((d & 255) << 18);
        }
    }
    __syncthreads();

    // phase D: per-bucket flush; 16-lane group per bucket, contiguous runs
    int grp = tid >> 4;              // 64 groups
    int gl  = tid & 15;
    for (int b = grp; b < nbkt; b += 64) {
        int o = off[b];
        int cc = off[b + 1] - o;
        if (cc <= 0) continue;
        int g = gbase[b];
        for (int k = gl; k < cc; k += 16)
            csrbuf[g + k] = ent[o + k];
    }
}

// ===== bucketize + fused gemm1 (R10-proven): one block (512t) per bucket =====
// hd1 fp8 e4m3 (16B/row, 3.2MB table -> fits 4MB per-XCD L2).
__global__ void __launch_bounds__(512) bucketize_gemm_kernel(
        const int* __restrict__ gcur, int* __restrict__ csrbuf,
        const float* __restrict__ x, const float* __restrict__ W1,
        int* __restrict__ row_beg, int* __restrict__ row_end,
        float* __restrict__ dinv, unsigned char* __restrict__ hd1, int n) {
    __shared__ int ent[CAP];     // 36 KB; reused as sW(8K)+part(17.4K) in phase 2
    __shared__ int cnt[256];
    __shared__ int off[256];
    __shared__ int cur[256];
    __shared__ int wsum2[4];
    int tid = threadIdx.x;
    int b = blockIdx.x;
    int base = b * CAP;
    int sz = gcur[b] - base;
    if (sz > CAP) sz = CAP;      // defensive (statically unreachable)
    int node0 = b << BKT_SHIFT;
    int nnodes = min(256, n - node0);
    for (int i = tid; i < sz; i += 512) ent[i] = csrbuf[base + i];
    if (tid < 256) cnt[tid] = 0;
    __syncthreads();
    for (int i = tid; i < sz; i += 512) atomicAdd(&cnt[ent[i] >> 18], 1);
    __syncthreads();
    // scan over 256 node-counts: shfl wave-scan (4 active waves) + fixup
    int v = (tid < 256) ? cnt[tid] : 0;
    int lane = tid & 63, w = tid >> 6;
    int vv = v;
#pragma unroll
    for (int d = 1; d < 64; d <<= 1) {
        int u = __shfl_up(vv, d, 64);
        if (lane >= d) vv += u;
    }
    if (tid < 256 && lane == 63) wsum2[w] = vv;
    __syncthreads();
    float di_reg = 0.f;          // this thread's node dinv (phase 2 reuse)
    if (tid < 256) {
        int wb = 0;
#pragma unroll
        for (int w2 = 0; w2 < 4; ++w2) wb += (w2 < w) ? wsum2[w2] : 0;
        int incl = wb + vv;
        int excl = incl - v;
        cur[tid] = excl;
        di_reg = rsqrtf((float)v + 1.0f);   // +1 self-loop
        if (tid < nnodes) {
            row_beg[node0 + tid] = base + excl;
            row_end[node0 + tid] = base + excl + v;
            dinv[node0 + tid] = di_reg;
        }
    }
    __syncthreads();
    for (int i = tid; i < sz; i += 512) {
        int p = ent[i];
        int dl = p >> 18;
        int pos = atomicAdd(&cur[dl], 1);
        csrbuf[base + pos] = p & 0x3FFFF;
    }
    __syncthreads();             // ent[] dead after scatter -> reuse
    // ===== phase 2: gemm1, all 512 threads (split-k by 2) =====
    float* sW   = (float*)ent;           // 2048 f32 = 8 KB
    float* part = (float*)(ent + 2048);  // 256*17 f32 = 17.4 KB
    for (int i = tid; i < INC * HC; i += 512) sW[i] = W1[i];
    __syncthreads();
    int r  = tid & 255;          // node slot
    int kh = tid >> 8;           // k-half (0: k 0..63, 1: k 64..127)
    float acc[HC];
#pragma unroll
    for (int f = 0; f < HC; ++f) acc[f] = 0.f;
    if (r < nnodes) {
        int node = node0 + r;
        const float4* xr = (const float4*)(x + (size_t)node * INC) + kh * 16;
        const float* wbase2 = &sW[kh * 64 * HC];
#pragma unroll 4
        for (int k4 = 0; k4 < 16; ++k4) {
            float4 xv = xr[k4];
            const float* wp = &wbase2[k4 * 4 * HC];
#pragma unroll
            for (int f = 0; f < HC; ++f)
                acc[f] += xv.x * wp[f] + xv.y * wp[HC + f] + xv.z * wp[2 * HC + f] + xv.w * wp[3 * HC + f];
        }
        if (kh == 1) {
#pragma unroll
            for (int f = 0; f < HC; ++f) part[r * 17 + f] = acc[f];
        }
    }
    __syncthreads();
    if (kh == 0 && r < nnodes) {
        int node = node0 + r;
        float t[HC];
#pragma unroll
        for (int f = 0; f < HC; ++f) t[f] = (acc[f] + part[r * 17 + f]) * di_reg;
        int4 st;
        st.x = pack4_fp8(t[0],  t[1],  t[2],  t[3]);
        st.y = pack4_fp8(t[4],  t[5],  t[6],  t[7]);
        st.z = pack4_fp8(t[8],  t[9],  t[10], t[11]);
        st.w = pack4_fp8(t[12], t[13], t[14], t[15]);
        *(int4*)(hd1 + (size_t)node * 16) = st;
    }
}

// ===== fp8 gather core (hd rows 16B): lane l of 16-lane group = (half
// h=l&1, slot k=l>>1); lane strides edges by 8 loading 8B (uint2) per edge.
// Verified in R14 via gather_fuse1 (absmax unchanged).
__device__ __forceinline__ float gather_row16_f8(
        const unsigned char* __restrict__ hd, const int* __restrict__ csr,
        int beg, int end, int node, int f) {
    int h = f & 1;           // which 8B half
    int k = f >> 1;          // edge slot 0..7
    float a0 = 0.f, a1 = 0.f, a2 = 0.f, a3 = 0.f;
    float a4 = 0.f, a5 = 0.f, a6 = 0.f, a7 = 0.f;
    int jj = beg + k;
    if (jj < end) {
        int s = csr[jj];
        jj += 8;
        for (; jj < end; jj += 8) {
            int sn = csr[jj];   // prefetch next edge's src (hides csr latency)
            uint2 v = *(const uint2*)(hd + ((size_t)s << 4) + (h << 3));
            acc4_fp8(v.x, a0, a1, a2, a3);
            acc4_fp8(v.y, a4, a5, a6, a7);
            s = sn;
        }
        uint2 v = *(const uint2*)(hd + ((size_t)s << 4) + (h << 3));
        acc4_fp8(v.x, a0, a1, a2, a3);
        acc4_fp8(v.y, a4, a5, a6, a7);
    }
#pragma unroll
    for (int m = 2; m <= 8; m <<= 1) {
        a0 += __shfl_xor(a0, m, 16); a1 += __shfl_xor(a1, m, 16);
        a2 += __shfl_xor(a2, m, 16); a3 += __shfl_xor(a3, m, 16);
        a4 += __shfl_xor(a4, m, 16); a5 += __shfl_xor(a5, m, 16);
        a6 += __shfl_xor(a6, m, 16); a7 += __shfl_xor(a7, m, 16);
    }
    // lane l exports element (l>>1)=k of half (l&1)=h = feature h*8+k;
    // dest f pulls from lane ((f&7)<<1)|(f>>3).
    float e = a0;
    e = (k == 1) ? a1 : e;
    e = (k == 2) ? a2 : e;
    e = (k == 3) ? a3 : e;
    e = (k == 4) ? a4 : e;
    e = (k == 5) ? a5 : e;
    e = (k == 6) ? a6 : e;
    e = (k == 7) ? a7 : e;
    float gsum = __shfl(e, ((f & 7) << 1) | (f >> 3), 16);
    return gsum + fp8_to_f(hd[(size_t)node * 16 + f]);
}

// ===== layer-1 gather (fp8 hd1) + fused W2; hd2 now ALSO fp8 =====
__global__ void __launch_bounds__(256) gather_fuse1_kernel(
        const unsigned char* __restrict__ hd1, const int* __restrict__ csr,
        const int* __restrict__ row_beg, const int* __restrict__ row_end,
        const float* __restrict__ dinv, const float* __restrict__ b1,
        const float* __restrict__ W2, unsigned char* __restrict__ hd2, int n) {
    __shared__ float sW[HC * 17];    // pitch 17: conflict-free column reads
    __shared__ float sb[HC];
    if (threadIdx.x < HC * HC) sW[(threadIdx.x >> 4) * 17 + (threadIdx.x & 15)] = W2[threadIdx.x];
    if (threadIdx.x < HC) sb[threadIdx.x] = b1[threadIdx.x];
    __syncthreads();
    int t = blockIdx.x * blockDim.x + threadIdx.x;
    int node = t >> 4;
    if (node >= n) return;
    int f = t & 15;
    float acc = gather_row16_f8(hd1, csr, row_beg[node], row_end[node], node, f);
    float di = dinv[node];
    float h1 = fmaxf(acc * di + sb[f], 0.f);
    float a2 = 0.f;
#pragma unroll
    for (int k = 0; k < HC; ++k) {
        float hk = __shfl(h1, k, 16);
        a2 += hk * sW[k * 17 + f];
    }
    // 1B/lane store; a wave's 64 lanes cover 64 contiguous bytes -> 1 line
    hd2[(size_t)node * 16 + f] = f_to_fp8(a2 * di);
}

// ===== layer-2 gather (fp8 hd2) + fused GRU + FC =====
__global__ void __launch_bounds__(256) gather_final_kernel(
        const unsigned char* __restrict__ hd2, const int* __restrict__ csr,
        const int* __restrict__ row_beg, const int* __restrict__ row_end,
        const float* __restrict__ dinv, const float* __restrict__ b2,
        const float* __restrict__ w_ih, const float* __restrict__ b_ih,
        const float* __restrict__ b_hh, const float* __restrict__ Wfc,
        const float* __restrict__ bfc, float* __restrict__ out, int n) {
    __shared__ float s_wih[3 * HC * 17];   // rows j, pitch 17
    __shared__ float s_wfc[OUTC * 17];
    __shared__ float s_bih[3 * HC], s_bhh[3 * HC], s_bfc[OUTC], s_b2[HC];
    for (int i = threadIdx.x; i < 3 * HC * HC; i += 256)
        s_wih[(i >> 4) * 17 + (i & 15)] = w_ih[i];
    for (int i = threadIdx.x; i < OUTC * HC; i += 256)
        s_wfc[(i >> 4) * 17 + (i & 15)] = Wfc[i];
    if (threadIdx.x < 3 * HC) { s_bih[threadIdx.x] = b_ih[threadIdx.x]; s_bhh[threadIdx.x] = b_hh[threadIdx.x]; }
    if (threadIdx.x < OUTC) s_bfc[threadIdx.x] = bfc[threadIdx.x];
    if (threadIdx.x < HC) s_b2[threadIdx.x] = b2[threadIdx.x];
    __syncthreads();
    int t = blockIdx.x * blockDim.x + threadIdx.x;
    int node = t >> 4;
    if (node >= n) return;
    int f = t & 15;
    float acc = gather_row16_f8(hd2, csr, row_beg[node], row_end[node], node, f);
    float h = fmaxf(acc * dinv[node] + s_b2[f], 0.f);
    // GRU (seq=1, h0=0 => gh = b_hh): lane f computes gate row j=f
    float ir = s_bih[f], iz = s_bih[HC + f], inn = s_bih[2 * HC + f];
#pragma unroll
    for (int k = 0; k < HC; ++k) {
        float hk = __shfl(h, k, 16);
        ir  += hk * s_wih[f * 17 + k];
        iz  += hk * s_wih[(HC + f) * 17 + k];
        inn += hk * s_wih[(2 * HC + f) * 17 + k];
    }
    float r = 1.f / (1.f + __expf(-(ir + s_bhh[f])));
    float z = 1.f / (1.f + __expf(-(iz + s_bhh[HC + f])));
    float nn = tanhf(inn + r * s_bhh[2 * HC + f]);
    float hs = (1.f - z) * nn;
    // FC: lane f computes outputs o=f and o=HC+f
    float a1 = s_bfc[f], a2 = s_bfc[HC + f];
#pragma unroll
    for (int k = 0; k < HC; ++k) {
        float hk = __shfl(hs, k, 16);
        a1 += hk * s_wfc[f * 17 + k];
        a2 += hk * s_wfc[(HC + f) * 17 + k];
    }
    float* orow = out + (size_t)node * OUTC;
    __builtin_nontemporal_store(a1, orow + f);
    __builtin_nontemporal_store(a2, orow + HC + f);
}

extern "C" void kernel_launch(void* const* d_in, const int* in_sizes, int n_in,
                              void* d_out, int out_size, void* d_ws, size_t ws_size,
                              hipStream_t stream) {
    const float* x     = (const float*)d_in[0];
    const int*   ei    = (const int*)d_in[1];
    const float* W1    = (const float*)d_in[3];
    const float* b1    = (const float*)d_in[4];
    const float* W2    = (const float*)d_in[5];
    const float* b2    = (const float*)d_in[6];
    const float* w_ih  = (const float*)d_in[7];
    // d_in[8] = w_hh unused: h0 == 0 => gh = b_hh
    const float* b_ih  = (const float*)d_in[9];
    const float* b_hh  = (const float*)d_in[10];
    const float* Wfc   = (const float*)d_in[11];
    const float* bfc   = (const float*)d_in[12];
    float* out = (float*)d_out;

    const int n = in_sizes[2];          // 200000
    const int e = in_sizes[1] / 2;      // 6400000
    const int* src = ei;
    const int* dst = ei + e;
    const int nbkt = (n + 255) >> BKT_SHIFT;   // 782

    // workspace layout (16B-aligned sections)
    int*   gcur    = (int*)d_ws;                     // 1024
    int*   row_beg = gcur + 1024;                    // n
    int*   row_end = row_beg + n;                    // n
    float* dinv    = (float*)(row_end + n);          // n
    int*   csrbuf  = (int*)(dinv + n);               // nbkt*CAP
    unsigned char* hd1 = (unsigned char*)(csrbuf + (size_t)nbkt * CAP);  // 16n B (3.2 MB, fp8)
    unsigned char* hd2 = hd1 + (size_t)n * 16;                           // 16n B (3.2 MB, fp8)

    const int B = 256;
    int gnf  = (int)(((long long)n * HC + B - 1) / B);  // 12500
    int gbin = (e + BINS - 1) / BINS;                   // 521

    init_gcur_kernel<<<(NBMAX + B - 1) / B, B, 0, stream>>>(gcur, nbkt);
    bin_kernel<<<gbin, 1024, 0, stream>>>(src, dst, gcur, csrbuf, e, nbkt);
    bucketize_gemm_kernel<<<nbkt, 512, 0, stream>>>(gcur, csrbuf, x, W1,
                                                    row_beg, row_end, dinv, hd1, n);
    gather_fuse1_kernel<<<gnf, B, 0, stream>>>(hd1, csrbuf, row_beg, row_end, dinv, b1, W2, hd2, n);
    gather_final_kernel<<<gnf, B, 0, stream>>>(hd2, csrbuf, row_beg, row_end, dinv, b2,
                                               w_ih, b_ih, b_hh, Wfc, bfc, out, n);
}

// Round 16
// 382.188 us; speedup vs baseline: 2.9499x; 1.0225x over previous
//
#include <hip/hip_runtime.h>
#include <hip/hip_fp16.h>
#include <hip/hip_fp8.h>
#include <math.h>

#define HC 16      // hidden
#define INC 128    // in_channels
#define OUTC 32    // out_channels
#define BKT_SHIFT 8            // 256 nodes per bucket
#define CAP 9216               // bucket edge capacity: E[8192] + 11 sigma
#define NBMAX 1024             // max buckets (782 actual)
#define BINS 12288             // 12 edges/thread * 1024 threads, exact
#define EPT 12                 // edges per thread

typedef _Float16 f16;
typedef float vf2 __attribute__((ext_vector_type(2)));

// ===== fp8 e4m3 (OCP) helpers: HW cvt builtins with header fallback =====
__device__ __forceinline__ void acc4_fp8(unsigned int w,
        float& a, float& b, float& c, float& d) {
#if __has_builtin(__builtin_amdgcn_cvt_pk_f32_fp8)
    vf2 lo = __builtin_amdgcn_cvt_pk_f32_fp8(w, false);
    vf2 hi = __builtin_amdgcn_cvt_pk_f32_fp8(w, true);
    a += lo[0]; b += lo[1]; c += hi[0]; d += hi[1];
#else
    __hip_fp8_e4m3 t;
    t.__x = w & 0xFF;         a += (float)t;
    t.__x = (w >> 8) & 0xFF;  b += (float)t;
    t.__x = (w >> 16) & 0xFF; c += (float)t;
    t.__x = (w >> 24) & 0xFF; d += (float)t;
#endif
}

__device__ __forceinline__ float fp8_to_f(unsigned char b) {
#if __has_builtin(__builtin_amdgcn_cvt_f32_fp8)
    return __builtin_amdgcn_cvt_f32_fp8((int)b, 0);
#else
    __hip_fp8_e4m3 t; t.__x = b; return (float)t;
#endif
}

__device__ __forceinline__ int pack4_fp8(float a, float b, float c, float d) {
#if __has_builtin(__builtin_amdgcn_cvt_pk_fp8_f32)
    int w = __builtin_amdgcn_cvt_pk_fp8_f32(a, b, 0, false);
    w = __builtin_amdgcn_cvt_pk_fp8_f32(c, d, w, true);
    return w;
#else
    __hip_fp8_e4m3 q0(a), q1(b), q2(c), q3(d);
    return (int)q0.__x | ((int)q1.__x << 8) | ((int)q2.__x << 16) | ((int)q3.__x << 24);
#endif
}

__device__ __forceinline__ unsigned char f_to_fp8(float a) {
#if __has_builtin(__builtin_amdgcn_cvt_pk_fp8_f32)
    int w = __builtin_amdgcn_cvt_pk_fp8_f32(a, a, 0, false);
    return (unsigned char)(w & 0xFF);
#else
    __hip_fp8_e4m3 q(a); return q.__x;
#endif
}

// ================= CSR build: LDS-staged binning =================
// R12 lesson: scattered 4B global writes do NOT L2-aggregate (WRITE=391MB).
// This LDS-staged design keeps CSR-build writes at ~38MB. Keep it.

__global__ void init_gcur_kernel(int* __restrict__ gcur, int nbkt) {
    int i = blockIdx.x * blockDim.x + threadIdx.x;
    if (i < nbkt) gcur[i] = i * CAP;
}

// 1024 threads/block, 62KB LDS -> 2 blocks/CU = 32 waves/CU.
// Packed entry: (dlocal << 18) | src
__global__ void __launch_bounds__(1024, 8) bin_kernel(
        const int* __restrict__ src, const int* __restrict__ dst,
        int* __restrict__ gcur, int* __restrict__ csrbuf, int e, int nbkt) {
    __shared__ int ent[BINS];        // 48 KB staging
    __shared__ int hist[NBMAX];      // counts -> local cursors (reused)
    __shared__ int off[NBMAX];       // exclusive offsets into staging
    __shared__ int gbase[NBMAX];     // reserved global bases
    __shared__ int wsum[16];         // per-wave scan partials
    int tid = threadIdx.x;
    int beg = blockIdx.x * BINS;
    int end = min(beg + BINS, e);
    if (end <= beg) return;

    // phase A: load edges (statically indexed), histogram
    int myd[EPT], mys[EPT];
#pragma unroll
    for (int u = 0; u < EPT; ++u) {
        int i = beg + u * 1024 + tid;
        myd[u] = (i < end) ? dst[i] : -1;
        mys[u] = (i < end) ? src[i] : 0;
    }
    hist[tid] = 0;                   // NBMAX == blockDim
    __syncthreads();
#pragma unroll
    for (int u = 0; u < EPT; ++u)
        if (myd[u] >= 0) atomicAdd(&hist[myd[u] >> BKT_SHIFT], 1);
    __syncthreads();

    // phase B: scan, thread t owns bucket t; shfl wave-scan + 16-wave fixup
    int c = hist[tid];
    int lane = tid & 63, wid = tid >> 6;
    int v = c;
#pragma unroll
    for (int d = 1; d < 64; d <<= 1) {
        int u = __shfl_up(v, d, 64);
        if (lane >= d) v += u;
    }
    if (lane == 63) wsum[wid] = v;
    __syncthreads();
    int wbase = 0;
#pragma unroll
    for (int w = 0; w < 16; ++w) wbase += (w < wid) ? wsum[w] : 0;
    int ex = wbase + v - c;          // exclusive prefix of c
    off[tid] = ex;                   // off[nbkt] == sz (hist beyond nbkt is 0)
    if (c) gbase[tid] = atomicAdd(&gcur[tid], c);
    hist[tid] = 0;                   // reuse as cursors
    __syncthreads();

    // phase C: group into staging
#pragma unroll
    for (int u = 0; u < EPT; ++u) {
        int d = myd[u];
        if (d >= 0) {
            int b = d >> BKT_SHIFT;
            int p = off[b] + atomicAdd(&hist[b], 1);
            ent[p] = (mys[u] & 0x3FFFF) | ((d & 255) << 18);
        }
    }
    __syncthreads();

    // phase D: per-bucket flush; 16-lane group per bucket, contiguous runs
    int grp = tid >> 4;              // 64 groups
    int gl  = tid & 15;
    for (int b = grp; b < nbkt; b += 64) {
        int o = off[b];
        int cc = off[b + 1] - o;
        if (cc <= 0) continue;
        int g = gbase[b];
        for (int k = gl; k < cc; k += 16)
            csrbuf[g + k] = ent[o + k];
    }
}

// ===== bucketize + fused gemm1, v2 phase-1 =====
// R16 restructure: (1) histogram straight from GLOBAL csrbuf (L2-warm from
// bin's flush) — no LDS stage-in pass; (2) scatter into LDS ent2 (LDS
// handles scatter natively); (3) flush ent2 -> csrbuf with coalesced int4
// stores (kills the 1.8x write amplification of 4B scattered stores).
// hd1 fp8 e4m3 (16B/row, 3.2MB table -> L2-resident for the gather).
__global__ void __launch_bounds__(512) bucketize_gemm_kernel(
        const int* __restrict__ gcur, int* __restrict__ csrbuf,
        const float* __restrict__ x, const float* __restrict__ W1,
        int* __restrict__ row_beg, int* __restrict__ row_end,
        float* __restrict__ dinv, unsigned char* __restrict__ hd1, int n) {
    __shared__ int ent2[CAP];    // 36 KB scatter target; reused as sW+part in phase 2
    __shared__ int cnt[256];
    __shared__ int cur[256];
    __shared__ int wsum2[4];
    int tid = threadIdx.x;
    int b = blockIdx.x;
    int base = b * CAP;
    int sz = gcur[b] - base;
    if (sz > CAP) sz = CAP;      // defensive (statically unreachable)
    int node0 = b << BKT_SHIFT;
    int nnodes = min(256, n - node0);
    if (tid < 256) cnt[tid] = 0;
    __syncthreads();
    // pass 1: per-node histogram from global (L2-warm)
    for (int i = tid; i < sz; i += 512)
        atomicAdd(&cnt[((unsigned)csrbuf[base + i]) >> 18], 1);
    __syncthreads();
    // scan over 256 node-counts: shfl wave-scan (4 active waves) + fixup
    int v = (tid < 256) ? cnt[tid] : 0;
    int lane = tid & 63, w = tid >> 6;
    int vv = v;
#pragma unroll
    for (int d = 1; d < 64; d <<= 1) {
        int u = __shfl_up(vv, d, 64);
        if (lane >= d) vv += u;
    }
    if (tid < 256 && lane == 63) wsum2[w] = vv;
    __syncthreads();
    float di_reg = 0.f;          // this thread's node dinv (phase 2 reuse)
    if (tid < 256) {
        int wb = 0;
#pragma unroll
        for (int w2 = 0; w2 < 4; ++w2) wb += (w2 < w) ? wsum2[w2] : 0;
        int incl = wb + vv;
        int excl = incl - v;
        cur[tid] = excl;
        di_reg = rsqrtf((float)v + 1.0f);   // +1 self-loop
        if (tid < nnodes) {
            row_beg[node0 + tid] = base + excl;
            row_end[node0 + tid] = base + excl + v;
            dinv[node0 + tid] = di_reg;
        }
    }
    __syncthreads();
    // pass 2: re-read global (L2-warm), scatter into LDS
    for (int i = tid; i < sz; i += 512) {
        int p = csrbuf[base + i];
        int pos = atomicAdd(&cur[((unsigned)p) >> 18], 1);
        ent2[pos] = p & 0x3FFFF;
    }
    __syncthreads();
    // flush: coalesced int4 stores (slab base 16B-aligned; tail garbage
    // lands beyond the last row_end, never read)
    int nq = (sz + 3) >> 2;
    for (int q = tid; q < nq; q += 512)
        ((int4*)(csrbuf + base))[q] = ((const int4*)ent2)[q];
    __syncthreads();             // ent2 dead -> reuse for gemm
    // ===== phase 2: gemm1, all 512 threads (split-k by 2) =====
    float* sW   = (float*)ent2;           // 2048 f32 = 8 KB
    float* part = (float*)(ent2 + 2048);  // 256*17 f32 = 17.4 KB
    for (int i = tid; i < INC * HC; i += 512) sW[i] = W1[i];
    __syncthreads();
    int r  = tid & 255;          // node slot
    int kh = tid >> 8;           // k-half (0: k 0..63, 1: k 64..127)
    float acc[HC];
#pragma unroll
    for (int f = 0; f < HC; ++f) acc[f] = 0.f;
    if (r < nnodes) {
        int node = node0 + r;
        const float4* xr = (const float4*)(x + (size_t)node * INC) + kh * 16;
        const float* wbase2 = &sW[kh * 64 * HC];
#pragma unroll 4
        for (int k4 = 0; k4 < 16; ++k4) {
            float4 xv = xr[k4];
            const float* wp = &wbase2[k4 * 4 * HC];
#pragma unroll
            for (int f = 0; f < HC; ++f)
                acc[f] += xv.x * wp[f] + xv.y * wp[HC + f] + xv.z * wp[2 * HC + f] + xv.w * wp[3 * HC + f];
        }
        if (kh == 1) {
#pragma unroll
            for (int f = 0; f < HC; ++f) part[r * 17 + f] = acc[f];
        }
    }
    __syncthreads();
    if (kh == 0 && r < nnodes) {
        int node = node0 + r;
        float t[HC];
#pragma unroll
        for (int f = 0; f < HC; ++f) t[f] = (acc[f] + part[r * 17 + f]) * di_reg;
        int4 st;
        st.x = pack4_fp8(t[0],  t[1],  t[2],  t[3]);
        st.y = pack4_fp8(t[4],  t[5],  t[6],  t[7]);
        st.z = pack4_fp8(t[8],  t[9],  t[10], t[11]);
        st.w = pack4_fp8(t[12], t[13], t[14], t[15]);
        *(int4*)(hd1 + (size_t)node * 16) = st;
    }
}

// ===== fp8 gather core (hd rows 16B): lane l of 16-lane group = (half
// h=l&1, slot k=l>>1); lane strides edges by 8 loading 8B (uint2) per edge.
// Verified R14/R15 (absmax at bf16 floor both rounds).
__device__ __forceinline__ float gather_row16_f8(
        const unsigned char* __restrict__ hd, const int* __restrict__ csr,
        int beg, int end, int node, int f) {
    int h = f & 1;           // which 8B half
    int k = f >> 1;          // edge slot 0..7
    float a0 = 0.f, a1 = 0.f, a2 = 0.f, a3 = 0.f;
    float a4 = 0.f, a5 = 0.f, a6 = 0.f, a7 = 0.f;
    int jj = beg + k;
    if (jj < end) {
        int s = csr[jj];
        jj += 8;
        for (; jj < end; jj += 8) {
            int sn = csr[jj];   // prefetch next edge's src (hides csr latency)
            uint2 v = *(const uint2*)(hd + ((size_t)s << 4) + (h << 3));
            acc4_fp8(v.x, a0, a1, a2, a3);
            acc4_fp8(v.y, a4, a5, a6, a7);
            s = sn;
        }
        uint2 v = *(const uint2*)(hd + ((size_t)s << 4) + (h << 3));
        acc4_fp8(v.x, a0, a1, a2, a3);
        acc4_fp8(v.y, a4, a5, a6, a7);
    }
#pragma unroll
    for (int m = 2; m <= 8; m <<= 1) {
        a0 += __shfl_xor(a0, m, 16); a1 += __shfl_xor(a1, m, 16);
        a2 += __shfl_xor(a2, m, 16); a3 += __shfl_xor(a3, m, 16);
        a4 += __shfl_xor(a4, m, 16); a5 += __shfl_xor(a5, m, 16);
        a6 += __shfl_xor(a6, m, 16); a7 += __shfl_xor(a7, m, 16);
    }
    // lane l exports element (l>>1)=k of half (l&1)=h = feature h*8+k;
    // dest f pulls from lane ((f&7)<<1)|(f>>3).
    float e = a0;
    e = (k == 1) ? a1 : e;
    e = (k == 2) ? a2 : e;
    e = (k == 3) ? a3 : e;
    e = (k == 4) ? a4 : e;
    e = (k == 5) ? a5 : e;
    e = (k == 6) ? a6 : e;
    e = (k == 7) ? a7 : e;
    float gsum = __shfl(e, ((f & 7) << 1) | (f >> 3), 16);
    return gsum + fp8_to_f(hd[(size_t)node * 16 + f]);
}

// ===== layer-1 gather (fp8 hd1) + fused W2; hd2 fp8 =====
__global__ void __launch_bounds__(256) gather_fuse1_kernel(
        const unsigned char* __restrict__ hd1, const int* __restrict__ csr,
        const int* __restrict__ row_beg, const int* __restrict__ row_end,
        const float* __restrict__ dinv, const float* __restrict__ b1,
        const float* __restrict__ W2, unsigned char* __restrict__ hd2, int n) {
    __shared__ float sW[HC * 17];    // pitch 17: conflict-free column reads
    __shared__ float sb[HC];
    if (threadIdx.x < HC * HC) sW[(threadIdx.x >> 4) * 17 + (threadIdx.x & 15)] = W2[threadIdx.x];
    if (threadIdx.x < HC) sb[threadIdx.x] = b1[threadIdx.x];
    __syncthreads();
    int t = blockIdx.x * blockDim.x + threadIdx.x;
    int node = t >> 4;
    if (node >= n) return;
    int f = t & 15;
    float acc = gather_row16_f8(hd1, csr, row_beg[node], row_end[node], node, f);
    float di = dinv[node];
    float h1 = fmaxf(acc * di + sb[f], 0.f);
    float a2 = 0.f;
#pragma unroll
    for (int k = 0; k < HC; ++k) {
        float hk = __shfl(h1, k, 16);
        a2 += hk * sW[k * 17 + f];
    }
    // 1B/lane store; a wave's 64 lanes cover 64 contiguous bytes -> 1 line
    hd2[(size_t)node * 16 + f] = f_to_fp8(a2 * di);
}

// ===== layer-2 gather (fp8 hd2) + fused GRU + FC =====
__global__ void __launch_bounds__(256) gather_final_kernel(
        const unsigned char* __restrict__ hd2, const int* __restrict__ csr,
        const int* __restrict__ row_beg, const int* __restrict__ row_end,
        const float* __restrict__ dinv, const float* __restrict__ b2,
        const float* __restrict__ w_ih, const float* __restrict__ b_ih,
        const float* __restrict__ b_hh, const float* __restrict__ Wfc,
        const float* __restrict__ bfc, float* __restrict__ out, int n) {
    __shared__ float s_wih[3 * HC * 17];   // rows j, pitch 17
    __shared__ float s_wfc[OUTC * 17];
    __shared__ float s_bih[3 * HC], s_bhh[3 * HC], s_bfc[OUTC], s_b2[HC];
    for (int i = threadIdx.x; i < 3 * HC * HC; i += 256)
        s_wih[(i >> 4) * 17 + (i & 15)] = w_ih[i];
    for (int i = threadIdx.x; i < OUTC * HC; i += 256)
        s_wfc[(i >> 4) * 17 + (i & 15)] = Wfc[i];
    if (threadIdx.x < 3 * HC) { s_bih[threadIdx.x] = b_ih[threadIdx.x]; s_bhh[threadIdx.x] = b_hh[threadIdx.x]; }
    if (threadIdx.x < OUTC) s_bfc[threadIdx.x] = bfc[threadIdx.x];
    if (threadIdx.x < HC) s_b2[threadIdx.x] = b2[threadIdx.x];
    __syncthreads();
    int t = blockIdx.x * blockDim.x + threadIdx.x;
    int node = t >> 4;
    if (node >= n) return;
    int f = t & 15;
    float acc = gather_row16_f8(hd2, csr, row_beg[node], row_end[node], node, f);
    float h = fmaxf(acc * dinv[node] + s_b2[f], 0.f);
    // GRU (seq=1, h0=0 => gh = b_hh): lane f computes gate row j=f
    float ir = s_bih[f], iz = s_bih[HC + f], inn = s_bih[2 * HC + f];
#pragma unroll
    for (int k = 0; k < HC; ++k) {
        float hk = __shfl(h, k, 16);
        ir  += hk * s_wih[f * 17 + k];
        iz  += hk * s_wih[(HC + f) * 17 + k];
        inn += hk * s_wih[(2 * HC + f) * 17 + k];
    }
    float r = 1.f / (1.f + __expf(-(ir + s_bhh[f])));
    float z = 1.f / (1.f + __expf(-(iz + s_bhh[HC + f])));
    float nn = tanhf(inn + r * s_bhh[2 * HC + f]);
    float hs = (1.f - z) * nn;
    // FC: lane f computes outputs o=f and o=HC+f
    float a1 = s_bfc[f], a2 = s_bfc[HC + f];
#pragma unroll
    for (int k = 0; k < HC; ++k) {
        float hk = __shfl(hs, k, 16);
        a1 += hk * s_wfc[f * 17 + k];
        a2 += hk * s_wfc[(HC + f) * 17 + k];
    }
    float* orow = out + (size_t)node * OUTC;
    __builtin_nontemporal_store(a1, orow + f);
    __builtin_nontemporal_store(a2, orow + HC + f);
}

extern "C" void kernel_launch(void* const* d_in, const int* in_sizes, int n_in,
                              void* d_out, int out_size, void* d_ws, size_t ws_size,
                              hipStream_t stream) {
    const float* x     = (const float*)d_in[0];
    const int*   ei    = (const int*)d_in[1];
    const float* W1    = (const float*)d_in[3];
    const float* b1    = (const float*)d_in[4];
    const float* W2    = (const float*)d_in[5];
    const float* b2    = (const float*)d_in[6];
    const float* w_ih  = (const float*)d_in[7];
    // d_in[8] = w_hh unused: h0 == 0 => gh = b_hh
    const float* b_ih  = (const float*)d_in[9];
    const float* b_hh  = (const float*)d_in[10];
    const float* Wfc   = (const float*)d_in[11];
    const float* bfc   = (const float*)d_in[12];
    float* out = (float*)d_out;

    const int n = in_sizes[2];          // 200000
    const int e = in_sizes[1] / 2;      // 6400000
    const int* src = ei;
    const int* dst = ei + e;
    const int nbkt = (n + 255) >> BKT_SHIFT;   // 782

    // workspace layout (16B-aligned sections)
    int*   gcur    = (int*)d_ws;                     // 1024
    int*   row_beg = gcur + 1024;                    // n
    int*   row_end = row_beg + n;                    // n
    float* dinv    = (float*)(row_end + n);          // n
    int*   csrbuf  = (int*)(dinv + n);               // nbkt*CAP
    unsigned char* hd1 = (unsigned char*)(csrbuf + (size_t)nbkt * CAP);  // 16n B (3.2 MB, fp8)
    unsigned char* hd2 = hd1 + (size_t)n * 16;                           // 16n B (3.2 MB, fp8)

    const int B = 256;
    int gnf  = (int)(((long long)n * HC + B - 1) / B);  // 12500
    int gbin = (e + BINS - 1) / BINS;                   // 521

    init_gcur_kernel<<<(NBMAX + B - 1) / B, B, 0, stream>>>(gcur, nbkt);
    bin_kernel<<<gbin, 1024, 0, stream>>>(src, dst, gcur, csrbuf, e, nbkt);
    bucketize_gemm_kernel<<<nbkt, 512, 0, stream>>>(gcur, csrbuf, x, W1,
                                                    row_beg, row_end, dinv, hd1, n);
    gather_fuse1_kernel<<<gnf, B, 0, stream>>>(hd1, csrbuf, row_beg, row_end, dinv, b1, W2, hd2, n);
    gather_final_kernel<<<gnf, B, 0, stream>>>(hd2, csrbuf, row_beg, row_end, dinv, b2,
                                               w_ih, b_ih, b_hh, Wfc, bfc, out, n);
}